// Round 4
// baseline (636.385 us; speedup 1.0000x reference)
//
#include <hip/hip_runtime.h>

// ---------- types ----------
typedef __attribute__((ext_vector_type(8))) short     bf16x8;   // MFMA A/B frag (4 VGPRs)
typedef __attribute__((ext_vector_type(4))) float     f32x4;    // MFMA C/D frag

// B=512, T=256, D=256, H=128, 4H=512
#define BSZ   512
#define TSZ   256
#define DSZ   256
#define HSZ   128
#define G4    512
#define OUT1  16777216L  // B*T*H
#define XSTR  262144L    // ushorts per t-slab = B * 4H

// ---------- helpers ----------
__device__ inline unsigned short f2bf(float f) {
  union { float f; unsigned int u; } v; v.f = f;
  unsigned int r = (v.u + 0x7FFFu + ((v.u >> 16) & 1u)) >> 16;
  return (unsigned short)r;
}
__device__ inline float bf_lo(unsigned int u) {  // low ushort -> float
  union { unsigned int u; float f; } v; v.u = u << 16; return v.f;
}
__device__ inline float bf_hi(unsigned int u) {  // high ushort -> float
  union { unsigned int u; float f; } v; v.u = u & 0xFFFF0000u; return v.f;
}
__device__ inline float sig_fast(float x)  { return 1.0f / (1.0f + __expf(-x)); }
__device__ inline float tanh_fast(float x) { return 1.0f - 2.0f / (__expf(2.0f * x) + 1.0f); }

// ---------- kernel 1: xw = x @ Wx.T + b, layout [t][b][colw*4+q] bf16 ----------
// Tiling unchanged from the R2 pass (x read exactly once, Wx resident in
// VGPRs, lane-linear LDS staging). Store index packs the 4 gate quadrants of
// each hidden column adjacently: gate n -> (q = n>>7, colw = n&127);
// elem = t*262144 + b*512 + colw*4 + q.
__global__ __launch_bounds__(512, 2)
void gemm_xw(const float* __restrict__ x, const float* __restrict__ Wx,
             const float* __restrict__ bias, unsigned short* __restrict__ xw) {
  __shared__ unsigned short aT[2][4096];   // [dbuf][(c*64 + lane)*8 + j], 8KB each

  const int tid = threadIdx.x;
  const int w   = tid >> 6;        // wave 0..7  (owns n-cols [64w,64w+64), stages chunk c=w)
  const int l   = tid & 63;
  const int p   = l & 15;
  const int r16 = l >> 4;          // 0..3
  const long m0blk = (long)blockIdx.x * 512;

  // ---- Wx -> resident B-frags (one-time) ----
  bf16x8 wf[4][8];                 // [n-tile][k-chunk]
#pragma unroll
  for (int nt = 0; nt < 4; ++nt) {
#pragma unroll
    for (int c = 0; c < 8; ++c) {
      const float* src = Wx + (long)(w * 64 + nt * 16 + p) * DSZ + c * 32 + r16 * 8;
      float4 lo = *(const float4*)src;
      float4 hi = *(const float4*)(src + 4);
      bf16x8 f;
      f[0] = (short)f2bf(lo.x); f[1] = (short)f2bf(lo.y);
      f[2] = (short)f2bf(lo.z); f[3] = (short)f2bf(lo.w);
      f[4] = (short)f2bf(hi.x); f[5] = (short)f2bf(hi.y);
      f[6] = (short)f2bf(hi.z); f[7] = (short)f2bf(hi.w);
      wf[nt][c] = f;
    }
  }
  float bn[4];
#pragma unroll
  for (int nt = 0; nt < 4; ++nt) bn[nt] = bias[w * 64 + nt * 16 + p];

  // ---- staging source: row = l&15, k-octet = 4w + r16 ----
  const float* asrc = x + (m0blk + (l & 15)) * DSZ + (4 * w + r16) * 8;
  const int wl8 = (w * 64 + l) * 8;          // ushort index of this thread's LDS dst

  // prologue: load tile 0
  float4 va = *(const float4*)asrc;
  float4 vb = *(const float4*)(asrc + 4);
  asrc += 16 * DSZ;

  for (int i = 0; i < 32; ++i) {
    // convert + lane-linear b128 write of tile i
    bf16x8 fr;
    fr[0] = (short)f2bf(va.x); fr[1] = (short)f2bf(va.y);
    fr[2] = (short)f2bf(va.z); fr[3] = (short)f2bf(va.w);
    fr[4] = (short)f2bf(vb.x); fr[5] = (short)f2bf(vb.y);
    fr[6] = (short)f2bf(vb.z); fr[7] = (short)f2bf(vb.w);
    *(bf16x8*)&aT[i & 1][wl8] = fr;

    // prefetch tile i+1 (stays in flight across the barrier)
    if (i < 31) {
      va = *(const float4*)asrc;
      vb = *(const float4*)(asrc + 4);
      asrc += 16 * DSZ;
    }

    asm volatile("s_waitcnt lgkmcnt(0)" ::: "memory");  // LDS write drained only
    __builtin_amdgcn_s_barrier();                       // no vmcnt(0) drain

    // compute tile i: 16 M-rows x 512 N
    f32x4 acc[4];
#pragma unroll
    for (int nt = 0; nt < 4; ++nt)
      acc[nt] = (f32x4){bn[nt], bn[nt], bn[nt], bn[nt]};

#pragma unroll
    for (int c = 0; c < 8; ++c) {
      bf16x8 aF = *(const bf16x8*)&aT[i & 1][(c * 64 + l) * 8];
#pragma unroll
      for (int nt = 0; nt < 4; ++nt)
        acc[nt] = __builtin_amdgcn_mfma_f32_16x16x32_bf16(aF, wf[nt][c], acc[nt], 0, 0, 0);
    }

    // store: m = blk*512 + i*16 + r16*4 + r -> t = (i&15)*16 + r16*4 + r, b = blk*2 + (i>>4)
    const int t0 = (i & 15) * 16 + r16 * 4;
    const int bb = blockIdx.x * 2 + (i >> 4);
    const int q  = w >> 1;
    const int colw0 = (w & 1) * 64 + p;   // + nt*16
    const long base0 = (long)t0 * XSTR + (long)bb * G4 + colw0 * 4 + q;
#pragma unroll
    for (int r = 0; r < 4; ++r) {
      const long rb = base0 + (long)r * XSTR;
#pragma unroll
      for (int nt = 0; nt < 4; ++nt)
        xw[rb + nt * 64] = f2bf(acc[nt][r]);
    }
  }
}

// ---------- kernel 2: recurrent scan via MFMA ----------
// v3: 512 blocks x 512 threads, ONE batch per block -> 2 independent
// barrier groups per CU (R2 had exactly 1 block/CU, so all 8 waves stalled
// together at every per-step barrier; MfmaUtil 19% matched the 128-MFMA/step
// issue time exactly -- pure latency exposure).
//   * occupancy 2 blocks/CU (launch_bounds(512,4), ~110 VGPR <= 128): block
//     A's stalls are filled by block B's compute.
//   * xw [t][b][colw*4+q]: ONE dwordx2 load per step (wave-contiguous 512B),
//     unpacked with 2 shl + 2 and (bf16 = f32 high half). Depth-2 prefetch
//     via even/odd buffers (each load has 2 full steps of slack).
//   * per-block work halved (1 batch): per-CU VALU demand ~flat vs R2.
__global__ __launch_bounds__(512, 4)
void lstm_rec_mfma(const unsigned short* __restrict__ xw, const float* __restrict__ Wh,
                   float* __restrict__ outH, float* __restrict__ outC,
                   float* __restrict__ outP) {
  __shared__ unsigned short h_lds[2 * 2048];   // [buf][c(4)][lane(64)][j(8)] bf16

  const int tid  = threadIdx.x;
  const int w    = tid >> 6;        // wave 0..7
  const int lane = tid & 63;
  const int p    = lane & 15;
  const int r16  = lane >> 4;       // 0..3
  const int b    = blockIdx.x;      // ONE batch per block

  // Wh -> B-frags (one-time). B[n=lane&15][k=(lane>>4)*8+j], n = q*128 + w*16 + p.
  bf16x8 whF[4][4];                 // [quadrant q][k-chunk c]
#pragma unroll
  for (int q = 0; q < 4; ++q) {
#pragma unroll
    for (int c = 0; c < 4; ++c) {
      const float* src = Wh + ((q * 128 + w * 16 + p) * HSZ + c * 32 + r16 * 8);
      float4 lo = *(const float4*)src;
      float4 hi = *(const float4*)(src + 4);
      bf16x8 f;
      f[0] = (short)f2bf(lo.x); f[1] = (short)f2bf(lo.y);
      f[2] = (short)f2bf(lo.z); f[3] = (short)f2bf(lo.w);
      f[4] = (short)f2bf(hi.x); f[5] = (short)f2bf(hi.y);
      f[6] = (short)f2bf(hi.z); f[7] = (short)f2bf(hi.w);
      whF[q][c] = f;
    }
  }

  // zero both h buffers (rows 1-15 stay zero forever)
  for (int i = tid; i < 2 * 2048; i += 512) h_lds[i] = 0;

  float cel0 = 0.f, pog0 = 0.f;

  const int colw = w * 16 + p;      // h/gate column owned by this lane
  const int c_  = colw >> 5, kk = colw & 31;
  const int lhi = (kk >> 3) << 4, jj = kk & 7;
  const int wr0 = c_ * 512 + lhi * 8 + jj;   // h row 0, A-frag layout

  // xw: elem = t*XSTR + b*512 + colw*4 + q ; one 8B load covers q=0..3
  const unsigned short* xb = xw + (long)b * G4 + colw * 4;

  // prologue: t=0, t=1
  uint2 xv0 = *(const uint2*)(xb);
  uint2 xv1 = *(const uint2*)(xb + XSTR);
  const unsigned short* xpn = xb + 2 * XSTR;   // next load target: t=2

  float* pH = outH + (long)b * TSZ * HSZ;
  float* pC = outC + (long)b * TSZ * HSZ;
  float* pP = outP + (long)b * TSZ * HSZ;

  f32x4 acc[4];
#pragma unroll
  for (int q = 0; q < 4; ++q) acc[q] = (f32x4){0.f, 0.f, 0.f, 0.f};

  __syncthreads();

#define STEP(RDOFF, WROFF, XV, PREF)                                            \
  {                                                                             \
    bf16x8 aF[4];                                                               \
    _Pragma("unroll")                                                           \
    for (int c = 0; c < 4; ++c)                                                 \
      aF[c] = *(const bf16x8*)&h_lds[(RDOFF) + c * 512 + lane * 8];             \
    /* unpack current xw: q0=lo.lo q1=lo.hi q2=hi.lo q3=hi.hi */                \
    acc[0][0] = bf_lo(XV.x);  acc[1][0] = bf_hi(XV.x);                          \
    acc[2][0] = bf_lo(XV.y);  acc[3][0] = bf_hi(XV.y);                          \
    if (PREF) { XV = *(const uint2*)xpn; xpn += XSTR; }                         \
    _Pragma("unroll")                                                           \
    for (int q = 0; q < 4; ++q)                                                 \
      _Pragma("unroll")                                                         \
      for (int c = 0; c < 4; ++c)                                               \
        acc[q] = __builtin_amdgcn_mfma_f32_16x16x32_bf16(aF[c], whF[q][c], acc[q], 0, 0, 0); \
    float i0 = sig_fast(acc[0][0]);                                             \
    float f0 = sig_fast(acc[1][0]);                                             \
    float o0 = 0.85f * sig_fast(acc[2][0]) + 0.15f * pog0;                      \
    float g0 = tanh_fast(acc[3][0]);                                            \
    cel0 = f0 * cel0 + i0 * g0;                                                 \
    float h0 = o0 * tanh_fast(cel0);                                            \
    pog0 = o0;                                                                  \
    if (lane < 16) {                                                            \
      pH[colw] = h0; pC[colw] = cel0; pP[colw] = o0;                            \
      h_lds[(WROFF) + wr0] = f2bf(h0);                                          \
    }                                                                           \
    pH += HSZ; pC += HSZ; pP += HSZ;                                            \
    asm volatile("s_waitcnt lgkmcnt(0)" ::: "memory");  /* LDS drained only */  \
    __builtin_amdgcn_s_barrier();                       /* no vmcnt(0) drain */ \
  }

  for (int it = 0; it < 127; ++it) {    // t = 0..253 (loads t+2)
    STEP(0, 2048, xv0, true)
    STEP(2048, 0, xv1, true)
  }
  STEP(0, 2048, xv0, false)             // t = 254
  STEP(2048, 0, xv1, false)             // t = 255
#undef STEP
}

// ---------- launch ----------
extern "C" void kernel_launch(void* const* d_in, const int* in_sizes, int n_in,
                              void* d_out, int out_size, void* d_ws, size_t ws_size,
                              hipStream_t stream) {
  const float* x    = (const float*)d_in[0];
  const float* Wx   = (const float*)d_in[1];
  const float* Wh   = (const float*)d_in[2];
  const float* bias = (const float*)d_in[3];

  float* outH = (float*)d_out;
  float* outC = outH + OUT1;
  float* outP = outC + OUT1;

  unsigned short* xwp = (unsigned short*)d_ws;  // bf16 xw, [t][b][colw*4+q], 134 MB

  dim3 g1(256), tb1(512);
  dim3 g2(512), tb2(512);

  gemm_xw<<<g1, tb1, 0, stream>>>(x, Wx, bias, xwp);
  lstm_rec_mfma<<<g2, tb2, 0, stream>>>(xwp, Wh, outH, outC, outP);
}